// Round 6
// baseline (97.514 us; speedup 1.0000x reference)
//
#include <hip/hip_runtime.h>
#include <hip/hip_bf16.h>

#define IN_F 256
#define OU_F 64
#define BKN 128          // nodes per bucket
#define BSHIFT 7
#define CHUNK 1024       // edges per partition block
#define STAGE_CAP 4096   // max records staged in LDS by csr_kernel

typedef __attribute__((ext_vector_type(8))) short short8;
typedef __attribute__((ext_vector_type(4))) float f32x4;

// ---------------- GEMM: hp(bf16) = h @ W via bf16 MFMA ----------------
// One block per 64-row tile. W staged per block into LDS transposed
// (Wt[col][k], stride 264 -> 2-lane/bank reads, free). h tile staged as
// bf16 in LDS with XOR swizzle (byte ^= (row&7)<<4) so A-frag ds_read_b128
// is 2-lane/bank. Global loads for staging are fully coalesced float4.
__global__ void __launch_bounds__(256)
gemm_mfma_kernel(const float* __restrict__ h, const float* __restrict__ W,
                 __hip_bfloat16* __restrict__ hp, int N)
{
    __shared__ unsigned short Wt[64][264];   // 33792 B, [col][k] bf16
    __shared__ uint4 hsv[2048];              // 32768 B, 64 rows x 512 B, swizzled
    unsigned char* hs = reinterpret_cast<unsigned char*>(hsv);
    const int t = threadIdx.x;

    // ---- stage W (256x64 fp32) -> Wt transposed bf16 ----
#pragma unroll
    for (int i = 0; i < 32; ++i) {
        int p  = t + i * 256;          // 8192 (col, k-pair) slots
        int c  = p & 63;
        int k0 = (p >> 6) << 1;
        float x = W[(size_t)k0 * OU_F + c];
        float y = W[(size_t)(k0 + 1) * OU_F + c];
        __hip_bfloat162 bb = __float22bfloat162_rn(make_float2(x, y));
        *reinterpret_cast<unsigned*>(&Wt[c][k0]) = *reinterpret_cast<unsigned*>(&bb);
    }

    // ---- stage h tile: wave w stages row i*4+w each iter, lanes = float4 cols ----
    const int rbase = blockIdx.x * 64;
    const int nrow  = min(64, N - rbase);
#pragma unroll
    for (int i = 0; i < 16; ++i) {
        int idx = t + i * 256;
        int r  = idx >> 6;             // row within tile
        int k4 = idx & 63;             // float4 column
        float4 v = make_float4(0.f, 0.f, 0.f, 0.f);
        if (r < nrow)
            v = reinterpret_cast<const float4*>(h)[(size_t)(rbase + r) * (IN_F / 4) + k4];
        __hip_bfloat162 lo = __float22bfloat162_rn(make_float2(v.x, v.y));
        __hip_bfloat162 hi = __float22bfloat162_rn(make_float2(v.z, v.w));
        unsigned boff = (unsigned)r * 512u + (((unsigned)k4 * 8u) ^ (((unsigned)r & 7u) << 4));
        uint2 pk;
        pk.x = *reinterpret_cast<unsigned*>(&lo);
        pk.y = *reinterpret_cast<unsigned*>(&hi);
        *reinterpret_cast<uint2*>(&hs[boff]) = pk;
    }
    __syncthreads();

    const int l    = t & 63;
    const int wv   = t >> 6;
    const int cl   = l & 15;          // A row-in-subtile / D col
    const int kg   = l >> 4;          // k-group
    const int rloc = wv * 16 + cl;    // A row within 64-row tile

    f32x4 acc[4];
#pragma unroll
    for (int nt = 0; nt < 4; ++nt) acc[nt] = (f32x4){0.f, 0.f, 0.f, 0.f};

#pragma unroll
    for (int ks = 0; ks < 8; ++ks) {
        unsigned aoff = (unsigned)rloc * 512u +
                        (((unsigned)(ks * 64 + kg * 16)) ^ (((unsigned)rloc & 7u) << 4));
        short8 af = *reinterpret_cast<const short8*>(&hs[aoff]);
#pragma unroll
        for (int nt = 0; nt < 4; ++nt) {
            short8 bf = *reinterpret_cast<const short8*>(&Wt[nt * 16 + cl][ks * 32 + kg * 8]);
            acc[nt] = __builtin_amdgcn_mfma_f32_16x16x32_bf16(af, bf, acc[nt], 0, 0, 0);
        }
    }

    // D: col = lane&15, row = (lane>>4)*4 + reg   (within wave's 16-row subtile)
#pragma unroll
    for (int nt = 0; nt < 4; ++nt)
#pragma unroll
        for (int rg = 0; rg < 4; ++rg) {
            int rr = rbase + wv * 16 + kg * 4 + rg;
            if (rr < N)
                hp[(size_t)rr * OU_F + nt * 16 + cl] = __float2bfloat16(acc[nt][rg]);
        }
}

// ---------------- bucket histogram ----------------
__global__ void __launch_bounds__(256)
hist_kernel(const int* __restrict__ col, int* __restrict__ bcnt, int E, int NB)
{
    __shared__ int lh[512];
    const int t = threadIdx.x;
    lh[t] = 0; lh[t + 256] = 0;
    __syncthreads();
    const int n4 = E >> 2;
    const int4* c4 = (const int4*)col;
    for (int i = blockIdx.x * 256 + t; i < n4; i += gridDim.x * 256) {
        int4 v = c4[i];
        atomicAdd(&lh[v.x >> BSHIFT], 1);
        atomicAdd(&lh[v.y >> BSHIFT], 1);
        atomicAdd(&lh[v.z >> BSHIFT], 1);
        atomicAdd(&lh[v.w >> BSHIFT], 1);
    }
    if (blockIdx.x == 0)
        for (int e = (n4 << 2) + t; e < E; e += 256)
            atomicAdd(&lh[col[e] >> BSHIFT], 1);
    __syncthreads();
    for (int i = t; i < NB; i += 256)
        if (lh[i]) atomicAdd(&bcnt[i], lh[i]);
}

// ---------------- exclusive scan of <=512 bucket counts (1 block) ----------------
__global__ void __launch_bounds__(256)
scan_kernel(const int* __restrict__ bcnt, int* __restrict__ boffs,
            int* __restrict__ bcursor, int NB)
{
    __shared__ int c[512];
    __shared__ int s[256];
    const int t = threadIdx.x;
    c[t]       = (t < NB)       ? bcnt[t] : 0;
    c[t + 256] = (t + 256 < NB) ? bcnt[t + 256] : 0;
    __syncthreads();
    s[t] = c[2 * t] + c[2 * t + 1];
    __syncthreads();
    for (int d = 1; d < 256; d <<= 1) {
        int v = (t >= d) ? s[t - d] : 0;
        __syncthreads();
        s[t] += v;
        __syncthreads();
    }
    int excl = (t > 0) ? s[t - 1] : 0;
    int e0 = excl;
    int e1 = excl + c[2 * t];
    if (2 * t < NB)     { boffs[2 * t]     = e0; bcursor[2 * t]     = e0; }
    if (2 * t + 1 < NB) { boffs[2 * t + 1] = e1; bcursor[2 * t + 1] = e1; }
    if (t == 255) boffs[NB] = s[255];
}

// ---------------- partition: counting-sort edges into buckets, coalesced writes ----------------
__global__ void __launch_bounds__(256)
partition_kernel(const int* __restrict__ row, const int* __restrict__ col,
                 const float* __restrict__ vals, int* __restrict__ bcursor,
                 int2* __restrict__ epk, int E, int NB)
{
    __shared__ int  hist[512];
    __shared__ int  X[512];        // local excl scan, then running cursor
    __shared__ int  gshift[512];   // global base - local base
    __shared__ int  s[256];
    __shared__ int2 stage[CHUNK];  // 8 KB
    __shared__ int  gpos[CHUNK];   // 4 KB

    const int t = threadIdx.x;
    const int base = blockIdx.x * CHUNK;
    const int n = min(CHUNK, E - base);

    hist[t] = 0; hist[t + 256] = 0;
    __syncthreads();

#pragma unroll
    for (int k = 0; k < CHUNK / 256; ++k) {
        int i = t + k * 256;
        if (i < n) atomicAdd(&hist[col[base + i] >> BSHIFT], 1);
    }
    __syncthreads();

    s[t] = hist[2 * t] + hist[2 * t + 1];
    __syncthreads();
    for (int d = 1; d < 256; d <<= 1) {
        int v = (t >= d) ? s[t - d] : 0;
        __syncthreads();
        s[t] += v;
        __syncthreads();
    }
    int excl = (t > 0) ? s[t - 1] : 0;
    X[2 * t]     = excl;
    X[2 * t + 1] = excl + hist[2 * t];
    __syncthreads();

    for (int i = t; i < NB; i += 256) {
        int hcnt = hist[i];
        int g = hcnt ? atomicAdd(&bcursor[i], hcnt) : 0;
        gshift[i] = g - X[i];
    }
    __syncthreads();

#pragma unroll
    for (int k = 0; k < CHUNK / 256; ++k) {
        int i = t + k * 256;
        if (i < n) {
            int e  = base + i;
            int cv = col[e];
            int b  = cv >> BSHIFT;
            int r  = atomicAdd(&X[b], 1);
            unsigned pk = (unsigned)row[e] | ((unsigned)(cv & (BKN - 1)) << 17);
            stage[r] = make_int2((int)pk, __float_as_int(vals[e]));
            gpos[r]  = gshift[b] + r;
        }
    }
    __syncthreads();

#pragma unroll
    for (int k = 0; k < CHUNK / 256; ++k) {
        int i = t + k * 256;
        if (i < n) epk[gpos[i]] = stage[i];   // runs of consecutive addresses
    }
}

// ---------------- within-bucket counting sort by node + CSR offsets ----------------
__global__ void __launch_bounds__(256)
csr_kernel(const int2* __restrict__ epk, const int* __restrict__ boffs,
           int2* __restrict__ epk2, int* __restrict__ node_offs,
           int N, int NB)
{
    __shared__ int  cnt[BKN];
    __shared__ int  sc[BKN];
    __shared__ int  cur[BKN];
    __shared__ int2 stage[STAGE_CAP];   // 32 KB
    const int t = threadIdx.x;
    const int b = blockIdx.x;
    const int s = boffs[b], e = boffs[b + 1];
    const int n = e - s;
    const int node0 = b << BSHIFT;

    if (t < BKN) cnt[t] = 0;
    __syncthreads();
    for (int i = t; i < n; i += 256)
        atomicAdd(&cnt[((unsigned)epk[s + i].x) >> 17], 1);
    __syncthreads();

    if (t < BKN) sc[t] = cnt[t];
    __syncthreads();
    for (int d = 1; d < BKN; d <<= 1) {
        int v = 0;
        if (t < BKN && t >= d) v = sc[t - d];
        __syncthreads();
        if (t < BKN) sc[t] += v;
        __syncthreads();
    }
    if (t < BKN) {
        int excl = sc[t] - cnt[t];
        cur[t] = excl;
        int node = node0 + t;
        if (node < N) node_offs[node] = s + excl;
    }
    if (b == NB - 1 && t == 0) node_offs[N] = e;
    __syncthreads();

    if (n <= STAGE_CAP) {
        for (int i = t; i < n; i += 256) {
            int2 r = epk[s + i];
            int pos = atomicAdd(&cur[((unsigned)r.x) >> 17], 1);
            stage[pos] = r;
        }
        __syncthreads();
        for (int i = t; i < n; i += 256)
            epk2[s + i] = stage[i];           // fully coalesced
    } else {
        for (int i = t; i < n; i += 256) {
            int2 r = epk[s + i];
            int pos = atomicAdd(&cur[((unsigned)r.x) >> 17], 1);
            epk2[s + pos] = r;
        }
    }
}

// ---------------- gather: one wave per destination node, no atomics ----------------
__global__ void __launch_bounds__(256)
gather_kernel(const __hip_bfloat16* __restrict__ hp, const int* __restrict__ node_offs,
              const int2* __restrict__ epk2, float* __restrict__ out, int N)
{
    int wid  = (int)((blockIdx.x * 256u + threadIdx.x) >> 6);   // node id
    int lane = threadIdx.x & 63;                                 // feature id
    if (wid >= N) return;
    int s = node_offs[wid], e = node_offs[wid + 1];
    float acc = 0.f;
    for (int base = s; base < e; base += 64) {
        int n = min(64, e - base);
        int2 m = make_int2(0, 0);
        if (lane < n) m = epk2[base + lane];
        int j = 0;
        for (; j + 4 <= n; j += 4) {
            unsigned r0 = (unsigned)__shfl(m.x, j)     & 0x1FFFFu;
            unsigned r1 = (unsigned)__shfl(m.x, j + 1) & 0x1FFFFu;
            unsigned r2 = (unsigned)__shfl(m.x, j + 2) & 0x1FFFFu;
            unsigned r3 = (unsigned)__shfl(m.x, j + 3) & 0x1FFFFu;
            float v0 = __int_as_float(__shfl(m.y, j));
            float v1 = __int_as_float(__shfl(m.y, j + 1));
            float v2 = __int_as_float(__shfl(m.y, j + 2));
            float v3 = __int_as_float(__shfl(m.y, j + 3));
            float x0 = __bfloat162float(hp[((size_t)r0 << 6) + lane]);
            float x1 = __bfloat162float(hp[((size_t)r1 << 6) + lane]);
            float x2 = __bfloat162float(hp[((size_t)r2 << 6) + lane]);
            float x3 = __bfloat162float(hp[((size_t)r3 << 6) + lane]);
            acc = fmaf(v0, x0, acc);
            acc = fmaf(v1, x1, acc);
            acc = fmaf(v2, x2, acc);
            acc = fmaf(v3, x3, acc);
        }
        for (; j < n; ++j) {
            unsigned r = (unsigned)__shfl(m.x, j) & 0x1FFFFu;
            float    v = __int_as_float(__shfl(m.y, j));
            acc = fmaf(v, __bfloat162float(hp[((size_t)r << 6) + lane]), acc);
        }
    }
    out[(size_t)wid * OU_F + lane] = acc;
}

// ---------------- fallback (atomic scatter) ----------------
__global__ void __launch_bounds__(256)
scatter_kernel(const __hip_bfloat16* __restrict__ hp, const int* __restrict__ row,
               const int* __restrict__ col, const float* __restrict__ vals,
               float* __restrict__ out, int E)
{
    unsigned int gid = blockIdx.x * 256u + threadIdx.x;
    int e = (int)(gid >> 6);
    if (e >= E) return;
    int f = (int)(gid & 63u);
    int r = row[e], c = col[e];
    float m = vals[e] * __bfloat162float(hp[(size_t)r * OU_F + f]);
    __hip_atomic_fetch_add(&out[(size_t)c * OU_F + f], m,
                           __ATOMIC_RELAXED, __HIP_MEMORY_SCOPE_AGENT);
}

extern "C" void kernel_launch(void* const* d_in, const int* in_sizes, int n_in,
                              void* d_out, int out_size, void* d_ws, size_t ws_size,
                              hipStream_t stream)
{
    const float* h    = (const float*)d_in[0];
    const float* W    = (const float*)d_in[1];
    const int*   row  = (const int*)d_in[2];
    const int*   col  = (const int*)d_in[3];
    const float* vals = (const float*)d_in[4];
    float*       out  = (float*)d_out;

    const int N = in_sizes[0] / IN_F;
    const int E = in_sizes[2];
    const int NB = (N + BKN - 1) / BKN;

    char*  ws  = (char*)d_ws;
    size_t off = 0;
    auto alloc = [&](size_t bytes) -> char* {
        char* p = ws + off;
        off = (off + bytes + 255) & ~(size_t)255;
        return p;
    };
    __hip_bfloat16* hp = (__hip_bfloat16*)alloc((size_t)N * OU_F * 2);
    int*   bcnt      = (int*)  alloc((size_t)NB * 4);
    int*   boffs     = (int*)  alloc((size_t)(NB + 1) * 4);
    int*   bcursor   = (int*)  alloc((size_t)NB * 4);
    int*   node_offs = (int*)  alloc((size_t)(N + 1) * 4);
    int2*  epk       = (int2*) alloc((size_t)E * 8);
    int2*  epk2      = (int2*) alloc((size_t)E * 8);
    const bool fits = (off <= ws_size) && (NB <= 512) && (N < 131072);

    const int ntiles = (N + 63) / 64;
    gemm_mfma_kernel<<<ntiles, 256, 0, stream>>>(h, W, hp, N);

    if (fits) {
        hipMemsetAsync(bcnt, 0, (size_t)NB * 4, stream);
        hist_kernel<<<256, 256, 0, stream>>>(col, bcnt, E, NB);
        scan_kernel<<<1, 256, 0, stream>>>(bcnt, boffs, bcursor, NB);
        partition_kernel<<<(E + CHUNK - 1) / CHUNK, 256, 0, stream>>>(
            row, col, vals, bcursor, epk, E, NB);
        csr_kernel<<<NB, 256, 0, stream>>>(epk, boffs, epk2, node_offs, N, NB);
        gather_kernel<<<(N + 3) / 4, 256, 0, stream>>>(hp, node_offs, epk2, out, N);
    } else {
        hipMemsetAsync(d_out, 0, (size_t)out_size * sizeof(float), stream);
        unsigned long long total = (unsigned long long)E * 64ull;
        unsigned int sgrid = (unsigned int)((total + 255ull) / 256ull);
        scatter_kernel<<<sgrid, 256, 0, stream>>>(hp, row, col, vals, out, E);
    }
}